// Round 2
// baseline (9527.756 us; speedup 1.0000x reference)
//
#include <hip/hip_runtime.h>
#include <math.h>

// ---------------- problem constants ----------------
#define S_PAD  224
#define NTOK   7168        // 32 * 224
#define DM     768
#define NH     12
#define HDIM   64
#define DMLP   3072
#define NBATCH 32
#define NLAYER 12
#define NPOOL  10
#define NSEL   5
#define NPLEN  5
#define NCLS   100
#define LN_EPS 1e-6f

typedef _Float16 f16_t;
typedef _Float16 f16x8 __attribute__((ext_vector_type(8)));
typedef float    floatx4 __attribute__((ext_vector_type(4)));

// async global->LDS, 16B per lane; lds ptr must be wave-uniform
__device__ inline void cp16_lds(void* lds, const void* gp) {
    __builtin_amdgcn_global_load_lds((const __attribute__((address_space(1))) void*)gp,
                                     (__attribute__((address_space(3))) void*)lds, 16, 0, 0);
}

// ---------------- weight transpose-convert: fp32 [K,N] -> fp16 [N,K] ----------------
__global__ void wconv_t(const float* __restrict__ W, f16_t* __restrict__ WT, int K, int N) {
    int layer = blockIdx.z;
    const float* Wp = W + (long)layer * K * N;
    f16_t* Tp = WT + (long)layer * K * N;
    __shared__ float tile[32][33];
    int n0 = blockIdx.x * 32, k0 = blockIdx.y * 32;
    int tc = threadIdx.x & 31, tr = threadIdx.x >> 5;   // 8 rows x 32 cols
    #pragma unroll
    for (int rr = 0; rr < 32; rr += 8)
        tile[tr + rr][tc] = Wp[(long)(k0 + tr + rr) * N + n0 + tc];
    __syncthreads();
    #pragma unroll
    for (int rr = 0; rr < 32; rr += 8)
        Tp[(long)(n0 + tr + rr) * K + k0 + tc] = (f16_t)tile[tc][tr + rr];
}

// ---------------- patchify: inputs [B,3,224,224] -> fp16 [B,224,768] (rows>=196 zero) ----
__global__ void patchify(const float* __restrict__ inp, f16_t* __restrict__ PATCH) {
    int s = blockIdx.x, b = blockIdx.y, t = threadIdx.x;
    f16_t* dst = PATCH + ((long)b * S_PAD + s) * DM;
    if (s >= 196) { for (int e = t; e < DM; e += 256) dst[e] = (f16_t)0.0f; return; }
    int py = s / 14, px = s % 14;
    for (int e = t; e < DM; e += 256) {
        int c = e >> 8, ph = (e >> 4) & 15, pw = e & 15;
        dst[e] = (f16_t)inp[(((long)b * 3 + c) * 224 + py * 16 + ph) * 224 + px * 16 + pw];
    }
}

// ---------------- generic MFMA GEMM: C[M,N] = A[M,K](f16) @ Bt[N,K]^T(f16) ----------------
// EPI: 0 = bias->fp32, 1 = bias->f16, 2 = bias+resid->fp32, 3 = gelu(bias)->f16
template<int EPI>
__global__ __launch_bounds__(256) void gemm_f16(
    const f16_t* __restrict__ A, const f16_t* __restrict__ Bt,
    const float* __restrict__ bias, const float* __restrict__ resid,
    float* __restrict__ outf, f16_t* __restrict__ outb, int N, int K)
{
    __shared__ __align__(16) f16_t ldsA[128 * 32];
    __shared__ __align__(16) f16_t ldsB[128 * 32];
    const int t = threadIdx.x;
    const int w = t >> 6, l = t & 63;
    const int lr = l & 15, quad = l >> 4;
    const long m0 = (long)blockIdx.x * 128, n0 = (long)blockIdx.y * 128;
    const int r = t >> 2, c8 = (t & 3) << 3;
    const f16_t* Ap = A + (m0 + r) * (long)K + c8;
    const f16_t* Bp = Bt + (n0 + r) * (long)K + c8;
    const int wm = (w >> 1) << 6, wn = (w & 1) << 6;
    char* lbA = (char*)ldsA + (w << 10);
    char* lbB = (char*)ldsB + (w << 10);
    floatx4 acc[4][4];
    #pragma unroll
    for (int i = 0; i < 4; i++)
        #pragma unroll
        for (int j = 0; j < 4; j++) acc[i][j] = (floatx4){0.f, 0.f, 0.f, 0.f};

    for (int k0 = 0; k0 < K; k0 += 32) {
        __syncthreads();
        cp16_lds(lbA,        Ap + k0);
        cp16_lds(lbA + 4096, Ap + (long)64 * K + k0);
        cp16_lds(lbB,        Bp + k0);
        cp16_lds(lbB + 4096, Bp + (long)64 * K + k0);
        __syncthreads();
        f16x8 af[4], bf[4];
        #pragma unroll
        for (int mi = 0; mi < 4; mi++)
            af[mi] = *(const f16x8*)((const char*)ldsA + ((wm + mi * 16 + lr) << 6) + (quad << 4));
        #pragma unroll
        for (int ni = 0; ni < 4; ni++)
            bf[ni] = *(const f16x8*)((const char*)ldsB + ((wn + ni * 16 + lr) << 6) + (quad << 4));
        #pragma unroll
        for (int mi = 0; mi < 4; mi++)
            #pragma unroll
            for (int ni = 0; ni < 4; ni++)
                acc[mi][ni] = __builtin_amdgcn_mfma_f32_16x16x32_f16(af[mi], bf[ni], acc[mi][ni], 0, 0, 0);
    }
    #pragma unroll
    for (int mi = 0; mi < 4; mi++) {
        const long row = m0 + wm + mi * 16 + quad * 4;
        #pragma unroll
        for (int ni = 0; ni < 4; ni++) {
            const long col = n0 + wn + ni * 16 + lr;
            const float bv = bias[col];
            #pragma unroll
            for (int rg = 0; rg < 4; rg++) {
                long idx = (row + rg) * (long)N + col;
                float v = acc[mi][ni][rg] + bv;
                if (EPI == 0) outf[idx] = v;
                else if (EPI == 1) outb[idx] = (f16_t)v;
                else if (EPI == 2) outf[idx] = v + resid[idx];
                else {
                    v = 0.5f * v * (1.0f + erff(v * 0.70710678118654752f));
                    outb[idx] = (f16_t)v;
                }
            }
        }
    }
}

// ---------------- assemble x0 = [cls | patch_emb] + pos; rows>=197 zero; writes X0 and X ----
__global__ void assemble_x0(const float* __restrict__ PE, const float* __restrict__ cls,
                            const float* __restrict__ pos, float* __restrict__ X0,
                            float* __restrict__ X) {
    int s = blockIdx.x, b = blockIdx.y, t = threadIdx.x;
    long o = ((long)b * S_PAD + s) * DM;
    for (int e = t; e < DM; e += 256) {
        float v;
        if (s == 0)        v = cls[e] + pos[e];
        else if (s <= 196) v = PE[((long)b * S_PAD + (s - 1)) * DM + e] + pos[(long)s * DM + e];
        else               v = 0.0f;
        X0[o + e] = v; X[o + e] = v;
    }
}

// ---------------- LN (fp32 in) -> fp16 out, one block per token row ----------------
__global__ __launch_bounds__(256) void ln_to_f16(const float* __restrict__ X,
        const float* __restrict__ gw, const float* __restrict__ gb, f16_t* __restrict__ out) {
    const long row = blockIdx.x;
    const int t = threadIdx.x;
    const float* x = X + row * DM;
    float v0 = x[t], v1 = x[t + 256], v2 = x[t + 512];
    float s = v0 + v1 + v2, ss = v0 * v0 + v1 * v1 + v2 * v2;
    #pragma unroll
    for (int off = 32; off; off >>= 1) { s += __shfl_down(s, off); ss += __shfl_down(ss, off); }
    __shared__ float sa[8];
    int w = t >> 6;
    if ((t & 63) == 0) { sa[w] = s; sa[4 + w] = ss; }
    __syncthreads();
    s = sa[0] + sa[1] + sa[2] + sa[3]; ss = sa[4] + sa[5] + sa[6] + sa[7];
    float mean = s * (1.0f / DM);
    float var = ss * (1.0f / DM) - mean * mean;
    float rs = rsqrtf(var + LN_EPS);
    f16_t* o = out + row * DM;
    o[t]       = (f16_t)((v0 - mean) * rs * gw[t]       + gb[t]);
    o[t + 256] = (f16_t)((v1 - mean) * rs * gw[t + 256] + gb[t + 256]);
    o[t + 512] = (f16_t)((v2 - mean) * rs * gw[t + 512] + gb[t + 512]);
}

// ---------------- attention ----------------
// scores[bh,i,j] = sum_d Q[i,d]*K[j,d]   (scale applied in softmax)
__global__ __launch_bounds__(256) void attn_qk(const f16_t* __restrict__ qkv, float* __restrict__ sc) {
    int bh = blockIdx.y, b = bh / NH, h = bh % NH;
    int w = threadIdx.x >> 6, l = threadIdx.x & 63;
    int tile = blockIdx.x * 4 + w;          // 196 tiles
    int ti = tile % 14, tj = tile / 14;
    int lr = l & 15, quad = l >> 4;
    const f16_t* Q = qkv + (long)b * S_PAD * 2304 + h * HDIM;
    const f16_t* Kp = Q + 768;
    int i = ti * 16 + lr, j = tj * 16 + lr;
    floatx4 acc = (floatx4){0.f, 0.f, 0.f, 0.f};
    #pragma unroll
    for (int kk = 0; kk < 64; kk += 32) {
        f16x8 a = *(const f16x8*)(Q  + (long)i * 2304 + kk + quad * 8);
        f16x8 bb = *(const f16x8*)(Kp + (long)j * 2304 + kk + quad * 8);
        acc = __builtin_amdgcn_mfma_f32_16x16x32_f16(a, bb, acc, 0, 0, 0);
    }
    float* dst = sc + (long)bh * S_PAD * S_PAD;
    #pragma unroll
    for (int rg = 0; rg < 4; rg++)
        dst[(long)(ti * 16 + quad * 4 + rg) * S_PAD + tj * 16 + lr] = acc[rg];
}

__global__ __launch_bounds__(256) void attn_softmax(const float* __restrict__ sc,
                                                    f16_t* __restrict__ P, int S) {
    long row = (long)blockIdx.x * 4 + (threadIdx.x >> 6);
    int l = threadIdx.x & 63;
    const float* src = sc + row * S_PAD;
    f16_t* dst = P + row * S_PAD;
    float v[4]; float m = -3.0e38f;
    #pragma unroll
    for (int it = 0; it < 4; it++) {
        int j = it * 64 + l;
        float x = (j < S) ? src[j] * 0.125f : -3.0e38f;
        v[it] = x; m = fmaxf(m, x);
    }
    #pragma unroll
    for (int off = 32; off; off >>= 1) m = fmaxf(m, __shfl_down(m, off));
    m = __shfl(m, 0);
    float sum = 0.f;
    #pragma unroll
    for (int it = 0; it < 4; it++) {
        int j = it * 64 + l;
        float e = (j < S) ? __expf(v[it] - m) : 0.f;
        v[it] = e; sum += e;
    }
    #pragma unroll
    for (int off = 32; off; off >>= 1) sum += __shfl_down(sum, off);
    sum = __shfl(sum, 0);
    float inv = 1.0f / sum;
    #pragma unroll
    for (int it = 0; it < 4; it++) {
        int j = it * 64 + l;
        if (j < S_PAD) dst[j] = (f16_t)(v[it] * inv);
    }
}

// VT[bh, d, j] = V[b, j, h, d]
__global__ void v_transpose(const f16_t* __restrict__ qkv, f16_t* __restrict__ vt) {
    int bh = blockIdx.y, b = bh / NH, h = bh % NH;
    int idx = blockIdx.x * 256 + threadIdx.x;        // over 64*224
    int d = idx / S_PAD, j = idx % S_PAD;
    vt[(long)bh * HDIM * S_PAD + idx] = qkv[((long)b * S_PAD + j) * 2304 + 1536 + h * HDIM + d];
}

// AO[b, i, h*64+d] = sum_j P[bh,i,j] * V[j,d]
__global__ __launch_bounds__(256) void attn_pv(const f16_t* __restrict__ P,
        const f16_t* __restrict__ vt, f16_t* __restrict__ AO) {
    int bh = blockIdx.y, b = bh / NH, h = bh % NH;
    int w = threadIdx.x >> 6, l = threadIdx.x & 63;
    int tile = blockIdx.x * 4 + w;          // 56 tiles: 14 x 4
    int ti = tile % 14, tj = tile / 14;
    int lr = l & 15, quad = l >> 4;
    const f16_t* Pp = P + (long)bh * S_PAD * S_PAD;
    const f16_t* Vt = vt + (long)bh * HDIM * S_PAD;
    int i = ti * 16 + lr, d = tj * 16 + lr;
    floatx4 acc = (floatx4){0.f, 0.f, 0.f, 0.f};
    for (int kk = 0; kk < S_PAD; kk += 32) {
        f16x8 a = *(const f16x8*)(Pp + (long)i * S_PAD + kk + quad * 8);
        f16x8 bb = *(const f16x8*)(Vt + (long)d * S_PAD + kk + quad * 8);
        acc = __builtin_amdgcn_mfma_f32_16x16x32_f16(a, bb, acc, 0, 0, 0);
    }
    f16_t* dst = AO + (long)b * S_PAD * DM + h * HDIM;
    #pragma unroll
    for (int rg = 0; rg < 4; rg++)
        dst[(long)(ti * 16 + quad * 4 + rg) * DM + tj * 16 + lr] = (f16_t)acc[rg];
}

// ---------------- routing ----------------
__global__ void cls_ln(const float* __restrict__ X, const float* __restrict__ gw,
                       const float* __restrict__ gb, float* __restrict__ q) {
    int b = blockIdx.x, t = threadIdx.x;
    const float* x = X + (long)b * S_PAD * DM;
    float v0 = x[t], v1 = x[t + 256], v2 = x[t + 512];
    float s = v0 + v1 + v2, ss = v0 * v0 + v1 * v1 + v2 * v2;
    #pragma unroll
    for (int off = 32; off; off >>= 1) { s += __shfl_down(s, off); ss += __shfl_down(ss, off); }
    __shared__ float sa[8];
    int w = t >> 6;
    if ((t & 63) == 0) { sa[w] = s; sa[4 + w] = ss; }
    __syncthreads();
    s = sa[0] + sa[1] + sa[2] + sa[3]; ss = sa[4] + sa[5] + sa[6] + sa[7];
    float mean = s * (1.0f / DM);
    float rs = rsqrtf(ss * (1.0f / DM) - mean * mean + LN_EPS);
    q[(long)b * DM + t]       = (v0 - mean) * rs * gw[t]       + gb[t];
    q[(long)b * DM + t + 256] = (v1 - mean) * rs * gw[t + 256] + gb[t + 256];
    q[(long)b * DM + t + 512] = (v2 - mean) * rs * gw[t + 512] + gb[t + 512];
}

__global__ void var_ssq(const float* __restrict__ var, float* __restrict__ ssq) {
    int p = blockIdx.x, chunk = blockIdx.y;   // grid (10, 36), 16384 elems per chunk
    const float* v = var + (long)p * DM * DM + (long)chunk * 16384;
    float s = 0.f;
    for (int i = threadIdx.x; i < 16384; i += 256) { float x = v[i]; s += x * x; }
    #pragma unroll
    for (int off = 32; off; off >>= 1) s += __shfl_down(s, off);
    __shared__ float sa[4];
    int w = threadIdx.x >> 6;
    if ((threadIdx.x & 63) == 0) sa[w] = s;
    __syncthreads();
    if (threadIdx.x == 0) atomicAdd(&ssq[p], sa[0] + sa[1] + sa[2] + sa[3]);
}

__global__ void route_coef(const float* __restrict__ ssq, const float* __restrict__ freq,
                           float* __restrict__ coef) {
    if (threadIdx.x == 0) {
        float fm = freq[0];
        for (int p = 1; p < NPOOL; p++) fm = fmaxf(fm, freq[p]);
        float w[NPOOL]; float n2 = 0.f;
        for (int p = 0; p < NPOOL; p++) { w[p] = fm - freq[p]; n2 += w[p] * w[p]; }
        float nrm = fmaxf(sqrtf(n2), 1e-12f);
        for (int p = 0; p < NPOOL; p++) {
            float wn = w[p] / nrm;
            coef[p] = 0.25f * logf(ssq[p]) + logf(fmaxf(wn, 1e-30f));
        }
    }
}

__global__ __launch_bounds__(256) void route_quad(const float* __restrict__ q,
        const float* __restrict__ kp, const float* __restrict__ iv,
        const float* __restrict__ coef, float* __restrict__ score) {
    int b = blockIdx.x, p = blockIdx.y, t = threadIdx.x;
    __shared__ float diff[DM];
    for (int e = t; e < DM; e += 256) diff[e] = q[(long)b * DM + e] - kp[(long)p * DM + e];
    __syncthreads();
    const float* M = iv + (long)p * DM * DM;
    float u0 = 0.f, u1 = 0.f, u2 = 0.f;
    for (int i = 0; i < DM; i++) {
        float di = diff[i];
        const float* r = M + (long)i * DM;
        u0 += di * r[t]; u1 += di * r[t + 256]; u2 += di * r[t + 512];
    }
    float part = u0 * diff[t] + u1 * diff[t + 256] + u2 * diff[t + 512];
    #pragma unroll
    for (int off = 32; off; off >>= 1) part += __shfl_down(part, off);
    __shared__ float sa[4];
    if ((t & 63) == 0) sa[t >> 6] = part;
    __syncthreads();
    if (t == 0) score[b * NPOOL + p] = -0.5f * (sa[0] + sa[1] + sa[2] + sa[3]) + coef[p];
}

__global__ void topk_kernel(const float* __restrict__ score, int* __restrict__ topk) {
    int b = threadIdx.x;
    if (b < NBATCH) {
        float s[NPOOL]; bool used[NPOOL];
        for (int p = 0; p < NPOOL; p++) { s[p] = score[b * NPOOL + p]; used[p] = false; }
        for (int k = 0; k < NSEL; k++) {
            int best = 0; float bv = 3.4e38f;
            for (int p = 0; p < NPOOL; p++)
                if (!used[p] && s[p] < bv) { bv = s[p]; best = p; }
            used[best] = true; topk[b * NSEL + k] = best;
        }
    }
}

// sx = [x0[:, :1] | prompts[topk]+pos0 | x0[:, 1:197]] ; rows>=222 zero
__global__ void assemble_sx(const float* __restrict__ X0, const float* __restrict__ prompts,
                            const float* __restrict__ pos, const int* __restrict__ topk,
                            float* __restrict__ X) {
    int s = blockIdx.x, b = blockIdx.y, t = threadIdx.x;
    long o = ((long)b * S_PAD + s) * DM;
    for (int e = t; e < DM; e += 256) {
        float v;
        if (s == 0) v = X0[(long)b * S_PAD * DM + e];
        else if (s <= 25) {
            int j = s - 1;
            int pr = topk[b * NSEL + j / NPLEN];
            v = prompts[((long)pr * NPLEN + j % NPLEN) * DM + e] + pos[e];
        } else if (s <= 221) {
            v = X0[((long)b * S_PAD + (s - 25)) * DM + e];
        } else v = 0.0f;
        X[o + e] = v;
    }
}

// feat[b] = mean_{j=1..25} LN(X[b,j]) * gw + gb
__global__ __launch_bounds__(256) void feat_ln_mean(const float* __restrict__ X,
        const float* __restrict__ gw, const float* __restrict__ gb, float* __restrict__ feat) {
    int b = blockIdx.x, t = threadIdx.x;
    __shared__ float sa[8];
    float f0 = 0.f, f1 = 0.f, f2 = 0.f;
    for (int j = 1; j <= NSEL * NPLEN; j++) {
        const float* x = X + ((long)b * S_PAD + j) * DM;
        float v0 = x[t], v1 = x[t + 256], v2 = x[t + 512];
        float s = v0 + v1 + v2, ss = v0 * v0 + v1 * v1 + v2 * v2;
        #pragma unroll
        for (int off = 32; off; off >>= 1) { s += __shfl_down(s, off); ss += __shfl_down(ss, off); }
        __syncthreads();
        int w = t >> 6;
        if ((t & 63) == 0) { sa[w] = s; sa[4 + w] = ss; }
        __syncthreads();
        s = sa[0] + sa[1] + sa[2] + sa[3]; ss = sa[4] + sa[5] + sa[6] + sa[7];
        float mean = s * (1.0f / DM);
        float rs = rsqrtf(ss * (1.0f / DM) - mean * mean + LN_EPS);
        f0 += (v0 - mean) * rs; f1 += (v1 - mean) * rs; f2 += (v2 - mean) * rs;
    }
    const float k = 1.0f / (NSEL * NPLEN);
    feat[(long)b * DM + t]       = f0 * k * gw[t]       + gb[t];
    feat[(long)b * DM + t + 256] = f1 * k * gw[t + 256] + gb[t + 256];
    feat[(long)b * DM + t + 512] = f2 * k * gw[t + 512] + gb[t + 512];
}

__global__ void head_gemm(const float* __restrict__ feat, const float* __restrict__ hw,
                          const float* __restrict__ hb, float* __restrict__ out) {
    int b = blockIdx.x, c = threadIdx.x;
    if (c < NCLS) {
        float a = hb[c];
        const float* f = feat + (long)b * DM;
        for (int k = 0; k < DM; k++) a += f[k] * hw[(long)k * NCLS + c];
        out[b * NCLS + c] = a;
    }
}

// ---------------- launch ----------------
extern "C" void kernel_launch(void* const* d_in, const int* in_sizes, int n_in,
                              void* d_out, int out_size, void* d_ws, size_t ws_size,
                              hipStream_t stream) {
    const float* inputs   = (const float*)d_in[0];
    const float* patch_w  = (const float*)d_in[1];
    const float* patch_b  = (const float*)d_in[2];
    const float* cls_tok  = (const float*)d_in[3];
    const float* pos_emb  = (const float*)d_in[4];
    const float* ln1_w    = (const float*)d_in[5];
    const float* ln1_b    = (const float*)d_in[6];
    const float* qkv_w    = (const float*)d_in[7];
    const float* qkv_b    = (const float*)d_in[8];
    const float* proj_w   = (const float*)d_in[9];
    const float* proj_b   = (const float*)d_in[10];
    const float* ln2_w    = (const float*)d_in[11];
    const float* ln2_b    = (const float*)d_in[12];
    const float* fc1_w    = (const float*)d_in[13];
    const float* fc1_b    = (const float*)d_in[14];
    const float* fc2_w    = (const float*)d_in[15];
    const float* fc2_b    = (const float*)d_in[16];
    const float* norm_w   = (const float*)d_in[17];
    const float* norm_b   = (const float*)d_in[18];
    const float* head_w   = (const float*)d_in[19];
    const float* head_b   = (const float*)d_in[20];
    const float* key_pool = (const float*)d_in[21];
    const float* freq     = (const float*)d_in[22];
    const float* prompts  = (const float*)d_in[23];
    const float* variance = (const float*)d_in[24];
    const float* inv_var  = (const float*)d_in[25];
    float* out = (float*)d_out;

    char* p = (char*)d_ws;
    auto alloc = [&](size_t bytes) { char* r = p; p += (bytes + 255) & ~(size_t)255; return r; };
    f16_t* WTpatch = (f16_t*)alloc(768UL * 768 * 2);
    f16_t* WTq  = (f16_t*)alloc(12UL * 2304 * 768 * 2);
    f16_t* WTpr = (f16_t*)alloc(12UL * 768 * 768 * 2);
    f16_t* WTf1 = (f16_t*)alloc(12UL * 3072 * 768 * 2);
    f16_t* WTf2 = (f16_t*)alloc(12UL * 768 * 3072 * 2);
    float*  X    = (float*)alloc((size_t)NTOK * DM * 4);
    float*  X0   = (float*)alloc((size_t)NTOK * DM * 4);
    f16_t* Hb   = (f16_t*)alloc((size_t)NTOK * DM * 2);
    f16_t* QKV  = (f16_t*)alloc((size_t)NTOK * 2304 * 2);
    f16_t* VT   = (f16_t*)alloc(384UL * HDIM * S_PAD * 2);
    f16_t* AO   = (f16_t*)alloc((size_t)NTOK * DM * 2);
    char* RSC    = alloc(384UL * S_PAD * S_PAD * 4);  // SC f32 | MID f16 | PE f32 (disjoint lifetimes)
    char* RP     = alloc(384UL * S_PAD * S_PAD * 2);  // P f16 | PATCH f16
    float* qv    = (float*)alloc(NBATCH * DM * 4);
    float* feat  = (float*)alloc(NBATCH * DM * 4);
    float* ssq   = (float*)alloc(NPOOL * 4);
    float* coef  = (float*)alloc(NPOOL * 4);
    float* score = (float*)alloc(NBATCH * NPOOL * 4);
    int*   tki   = (int*)alloc(NBATCH * NSEL * 4);
    float*  SC   = (float*)RSC;
    f16_t* MID  = (f16_t*)RSC;
    float*  PE   = (float*)RSC;
    f16_t* Pm   = (f16_t*)RP;
    f16_t* PATCH= (f16_t*)RP;

    // ---- weights -> f16 transposed ----
    wconv_t<<<dim3(768/32, 768/32, 1), 256, 0, stream>>>(patch_w, WTpatch, 768, 768);
    wconv_t<<<dim3(2304/32, 768/32, 12), 256, 0, stream>>>(qkv_w, WTq, 768, 2304);
    wconv_t<<<dim3(768/32, 768/32, 12), 256, 0, stream>>>(proj_w, WTpr, 768, 768);
    wconv_t<<<dim3(3072/32, 768/32, 12), 256, 0, stream>>>(fc1_w, WTf1, 768, 3072);
    wconv_t<<<dim3(768/32, 3072/32, 12), 256, 0, stream>>>(fc2_w, WTf2, 3072, 768);

    // ---- embed ----
    patchify<<<dim3(S_PAD, NBATCH), 256, 0, stream>>>(inputs, PATCH);
    gemm_f16<0><<<dim3(56, 6), 256, 0, stream>>>(PATCH, WTpatch, patch_b, nullptr, PE, nullptr, 768, 768);
    assemble_x0<<<dim3(S_PAD, NBATCH), 256, 0, stream>>>(PE, cls_tok, pos_emb, X0, X);

    auto run_layers = [&](int S) {
        for (int l = 0; l < NLAYER; l++) {
            ln_to_f16<<<NTOK, 256, 0, stream>>>(X, ln1_w + l * DM, ln1_b + l * DM, Hb);
            gemm_f16<1><<<dim3(56, 18), 256, 0, stream>>>(Hb, WTq + (long)l * 2304 * 768,
                qkv_b + l * 2304, nullptr, nullptr, QKV, 2304, 768);
            v_transpose<<<dim3(56, 384), 256, 0, stream>>>(QKV, VT);
            attn_qk<<<dim3(49, 384), 256, 0, stream>>>(QKV, SC);
            attn_softmax<<<21504, 256, 0, stream>>>(SC, Pm, S);
            attn_pv<<<dim3(14, 384), 256, 0, stream>>>(Pm, VT, AO);
            gemm_f16<2><<<dim3(56, 6), 256, 0, stream>>>(AO, WTpr + (long)l * 768 * 768,
                proj_b + l * DM, X, X, nullptr, 768, 768);
            ln_to_f16<<<NTOK, 256, 0, stream>>>(X, ln2_w + l * DM, ln2_b + l * DM, Hb);
            gemm_f16<3><<<dim3(56, 24), 256, 0, stream>>>(Hb, WTf1 + (long)l * 3072 * 768,
                fc1_b + l * DMLP, nullptr, nullptr, MID, 3072, 768);
            gemm_f16<2><<<dim3(56, 6), 256, 0, stream>>>(MID, WTf2 + (long)l * 768 * 3072,
                fc2_b + l * DM, X, X, nullptr, 768, 3072);
        }
    };

    // ---- pass 1 (S=197) ----
    run_layers(197);

    // ---- routing ----
    cls_ln<<<NBATCH, 256, 0, stream>>>(X, norm_w, norm_b, qv);
    hipMemsetAsync(ssq, 0, NPOOL * 4, stream);
    var_ssq<<<dim3(NPOOL, 36), 256, 0, stream>>>(variance, ssq);
    route_coef<<<1, 64, 0, stream>>>(ssq, freq, coef);
    route_quad<<<dim3(NBATCH, NPOOL), 256, 0, stream>>>(qv, key_pool, inv_var, coef, score);
    topk_kernel<<<1, 32, 0, stream>>>(score, tki);
    assemble_sx<<<dim3(S_PAD, NBATCH), 256, 0, stream>>>(X0, prompts, pos_emb, tki, X);

    // ---- pass 2 (S=222) ----
    run_layers(222);

    // ---- head ----
    feat_ln_mean<<<NBATCH, 256, 0, stream>>>(X, norm_w, norm_b, feat);
    head_gemm<<<NBATCH, 128, 0, stream>>>(feat, head_w, head_b, out);
    (void)in_sizes; (void)n_in; (void)out_size; (void)ws_size;
}

// Round 4
// 7006.205 us; speedup vs baseline: 1.3599x; 1.3599x over previous
//
#include <hip/hip_runtime.h>
#include <math.h>

// ---------------- problem constants ----------------
#define S_PAD  224
#define NTOK   7168        // 32 * 224
#define DM     768
#define NH     12
#define HDIM   64
#define DMLP   3072
#define NBATCH 32
#define NLAYER 12
#define NPOOL  10
#define NSEL   5
#define NPLEN  5
#define NCLS   100
#define LN_EPS 1e-6f

typedef _Float16 f16_t;
typedef _Float16 f16x8 __attribute__((ext_vector_type(8)));
typedef float    floatx4 __attribute__((ext_vector_type(4)));

// async global->LDS: dest = wave-uniform lds base + lane*16B; src per-lane
__device__ inline void cp16_lds(void* lds, const void* gp) {
    __builtin_amdgcn_global_load_lds((const __attribute__((address_space(1))) void*)gp,
                                     (__attribute__((address_space(3))) void*)lds, 16, 0, 0);
}

// ---------------- weight transpose-convert: fp32 [K,N] -> fp16 [N,K] ----------------
__global__ void wconv_t(const float* __restrict__ W, f16_t* __restrict__ WT, int K, int N) {
    int layer = blockIdx.z;
    const float* Wp = W + (long)layer * K * N;
    f16_t* Tp = WT + (long)layer * K * N;
    __shared__ float tile[32][33];
    int n0 = blockIdx.x * 32, k0 = blockIdx.y * 32;
    int tc = threadIdx.x & 31, tr = threadIdx.x >> 5;   // 8 rows x 32 cols
    #pragma unroll
    for (int rr = 0; rr < 32; rr += 8)
        tile[tr + rr][tc] = Wp[(long)(k0 + tr + rr) * N + n0 + tc];
    __syncthreads();
    #pragma unroll
    for (int rr = 0; rr < 32; rr += 8)
        Tp[(long)(n0 + tr + rr) * K + k0 + tc] = (f16_t)tile[tc][tr + rr];
}

// ---------------- patchify: inputs [B,3,224,224] -> fp16 [B,224,768] (rows>=196 zero) ----
__global__ void patchify(const float* __restrict__ inp, f16_t* __restrict__ PATCH) {
    int s = blockIdx.x, b = blockIdx.y, t = threadIdx.x;
    f16_t* dst = PATCH + ((long)b * S_PAD + s) * DM;
    if (s >= 196) { for (int e = t; e < DM; e += 256) dst[e] = (f16_t)0.0f; return; }
    int py = s / 14, px = s % 14;
    for (int e = t; e < DM; e += 256) {
        int c = e >> 8, ph = (e >> 4) & 15, pw = e & 15;
        dst[e] = (f16_t)inp[(((long)b * 3 + c) * 224 + py * 16 + ph) * 224 + px * 16 + pw];
    }
}

// ---------------- generic MFMA GEMM: C[M,N] = A[M,K](f16) @ Bt[N,K]^T(f16) ----------------
// EPI: 0 = bias->fp32, 1 = bias->f16, 2 = bias+resid->fp32, 3 = gelu(bias)->f16
// BM: 128 (big-N) or 64 (N=768: doubles grid for occupancy)
template<int EPI, int BM>
__global__ __launch_bounds__(256) void gemm_f16(
    const f16_t* __restrict__ A, const f16_t* __restrict__ Bt,
    const float* __restrict__ bias, const float* __restrict__ resid,
    float* __restrict__ outf, f16_t* __restrict__ outb, int N, int K)
{
    constexpr int MI = BM / 32;                 // acc tiles per wave along M
    __shared__ __align__(16) f16_t ldsA[BM * 32];
    __shared__ __align__(16) f16_t ldsB[128 * 32];
    const int t = threadIdx.x;
    const int w = t >> 6, l = t & 63;
    const int lr = l & 15, quad = l >> 4;
    const long m0 = (long)blockIdx.x * BM, n0 = (long)blockIdx.y * 128;
    const int r = t >> 2, c8 = (t & 3) << 3;
    const f16_t* Ap = A + (m0 + (r % BM)) * (long)K + c8;
    const f16_t* Bp = Bt + (n0 + r) * (long)K + c8;
    const int wm = (w >> 1) * (BM >> 1), wn = (w & 1) << 6;
    char* lbA = (char*)ldsA + (w << 10);
    char* lbB = (char*)ldsB + (w << 10);
    floatx4 acc[MI][4];
    #pragma unroll
    for (int i = 0; i < MI; i++)
        #pragma unroll
        for (int j = 0; j < 4; j++) acc[i][j] = (floatx4){0.f, 0.f, 0.f, 0.f};

    for (int k0 = 0; k0 < K; k0 += 32) {
        __syncthreads();
        cp16_lds(lbA, Ap + k0);
        if (BM == 128) cp16_lds(lbA + 4096, Ap + (long)64 * K + k0);
        cp16_lds(lbB,        Bp + k0);
        cp16_lds(lbB + 4096, Bp + (long)64 * K + k0);
        __syncthreads();
        f16x8 af[MI], bf[4];
        #pragma unroll
        for (int mi = 0; mi < MI; mi++)
            af[mi] = *(const f16x8*)((const char*)ldsA + ((wm + mi * 16 + lr) << 6) + (quad << 4));
        #pragma unroll
        for (int ni = 0; ni < 4; ni++)
            bf[ni] = *(const f16x8*)((const char*)ldsB + ((wn + ni * 16 + lr) << 6) + (quad << 4));
        #pragma unroll
        for (int mi = 0; mi < MI; mi++)
            #pragma unroll
            for (int ni = 0; ni < 4; ni++)
                acc[mi][ni] = __builtin_amdgcn_mfma_f32_16x16x32_f16(af[mi], bf[ni], acc[mi][ni], 0, 0, 0);
    }
    #pragma unroll
    for (int mi = 0; mi < MI; mi++) {
        const long row = m0 + wm + mi * 16 + quad * 4;
        #pragma unroll
        for (int ni = 0; ni < 4; ni++) {
            const long col = n0 + wn + ni * 16 + lr;
            const float bv = bias[col];
            #pragma unroll
            for (int rg = 0; rg < 4; rg++) {
                long idx = (row + rg) * (long)N + col;
                float v = acc[mi][ni][rg] + bv;
                if (EPI == 0) outf[idx] = v;
                else if (EPI == 1) outb[idx] = (f16_t)v;
                else if (EPI == 2) outf[idx] = v + resid[idx];
                else {
                    v = 0.5f * v * (1.0f + erff(v * 0.70710678118654752f));
                    outb[idx] = (f16_t)v;
                }
            }
        }
    }
}

// ---------------- assemble x0 = [cls | patch_emb] + pos; rows>=197 zero; writes X0 and X ----
__global__ void assemble_x0(const float* __restrict__ PE, const float* __restrict__ cls,
                            const float* __restrict__ pos, float* __restrict__ X0,
                            float* __restrict__ X) {
    int s = blockIdx.x, b = blockIdx.y, t = threadIdx.x;
    long o = ((long)b * S_PAD + s) * DM;
    for (int e = t; e < DM; e += 256) {
        float v;
        if (s == 0)        v = cls[e] + pos[e];
        else if (s <= 196) v = PE[((long)b * S_PAD + (s - 1)) * DM + e] + pos[(long)s * DM + e];
        else               v = 0.0f;
        X0[o + e] = v; X[o + e] = v;
    }
}

// ---------------- LN (fp32 in) -> fp16 out, one block per token row ----------------
__global__ __launch_bounds__(256) void ln_to_f16(const float* __restrict__ X,
        const float* __restrict__ gw, const float* __restrict__ gb, f16_t* __restrict__ out) {
    const long row = blockIdx.x;
    const int t = threadIdx.x;
    const float* x = X + row * DM;
    float v0 = x[t], v1 = x[t + 256], v2 = x[t + 512];
    float s = v0 + v1 + v2, ss = v0 * v0 + v1 * v1 + v2 * v2;
    #pragma unroll
    for (int off = 32; off; off >>= 1) { s += __shfl_down(s, off); ss += __shfl_down(ss, off); }
    __shared__ float sa[8];
    int w = t >> 6;
    if ((t & 63) == 0) { sa[w] = s; sa[4 + w] = ss; }
    __syncthreads();
    s = sa[0] + sa[1] + sa[2] + sa[3]; ss = sa[4] + sa[5] + sa[6] + sa[7];
    float mean = s * (1.0f / DM);
    float var = ss * (1.0f / DM) - mean * mean;
    float rs = rsqrtf(var + LN_EPS);
    f16_t* o = out + row * DM;
    o[t]       = (f16_t)((v0 - mean) * rs * gw[t]       + gb[t]);
    o[t + 256] = (f16_t)((v1 - mean) * rs * gw[t + 256] + gb[t + 256]);
    o[t + 512] = (f16_t)((v2 - mean) * rs * gw[t + 512] + gb[t + 512]);
}

// ---------------- V transpose: QKV -> VTg[bh][64][224], LDS-staged ----------------
__global__ __launch_bounds__(256) void v_trans(const f16_t* __restrict__ qkv,
                                               f16_t* __restrict__ vtg) {
    int bh = blockIdx.x, b = bh / NH, h = bh % NH;
    __shared__ __align__(16) char lds[32768];       // V[j][d] rows padded to 72 elems (9 chunks)
    int t = threadIdx.x, w = t >> 6, l = t & 63;
    const f16_t* Vb = qkv + (long)b * S_PAD * 2304 + 1536 + h * HDIM;
    #pragma unroll
    for (int q = 0; q < 8; q++) {
        int c0 = q * 256 + w * 64;        // wave-uniform dest base (chunks)
        int cc = c0 + l;
        int j = cc / 9, part = cc - j * 9;
        if (j > 223) j = 223;
        if (part > 7) part = 7;
        cp16_lds(lds + (size_t)c0 * 16, Vb + (long)j * 2304 + part * 8);
    }
    __syncthreads();
    const f16_t* Vs = (const f16_t*)lds;
    f16_t* dst = vtg + (long)bh * HDIM * S_PAD;
    #pragma unroll
    for (int it = 0; it < 56; it++) {
        int e = it * 256 + t;             // over 64*224
        int d = e / S_PAD, j = e - d * S_PAD;
        dst[e] = Vs[j * 72 + d];
    }
}

// ---------------- fused attention: QK^T -> softmax -> PV, one kernel ----------------
// grid (4, 384): block handles rows [iblk*64, iblk*64+64) of one (b,h).
// NOTE: 4*64 = 256 > S_PAD=224 -> last block's waves 2,3 are out of range:
// Q reads are clamped to row 223, AO stores are predicated (wave-uniform,
// since 224 = 14*16 aligns with per-wave 16-row groups).
__global__ __launch_bounds__(256) void attn_fused(const f16_t* __restrict__ qkv,
        const f16_t* __restrict__ vtg, f16_t* __restrict__ AO, int S) {
    int bh = blockIdx.y, b = bh / NH, h = bh % NH;
    int i0 = blockIdx.x * 64;
    int t = threadIdx.x, w = t >> 6, l = t & 63;
    int lr = l & 15, quad = l >> 4;
    // LDS: Ksh [224][72] = 32256B + 512B DMA pad = 32768; Vt [64][232] = 29696. Total 62464.
    // Psh (per wave 16x232) reuses the Ksh region after the QK barrier.
    __shared__ __align__(16) char lds[62464];
    const f16_t* Kb = qkv + (long)b * S_PAD * 2304 + 768 + h * HDIM;
    const f16_t* Qb = qkv + (long)b * S_PAD * 2304 + h * HDIM;
    const f16_t* Vg = vtg + (long)bh * HDIM * S_PAD;

    // ---- DMA K rows into padded Ksh: 224 rows x 9 chunks = 2016, padded to 2048 ----
    #pragma unroll
    for (int q = 0; q < 8; q++) {
        int c0 = q * 256 + w * 64;
        int cc = c0 + l;
        int j = cc / 9, part = cc - j * 9;
        if (j > 223) j = 223;
        if (part > 7) part = 7;
        cp16_lds(lds + (size_t)c0 * 16, Kb + (long)j * 2304 + part * 8);
    }
    // ---- DMA VT rows into padded Vt: 64 rows x 29 chunks = 1856 (= 29 x 64, exact) ----
    #pragma unroll
    for (int q = 0; q < 8; q++) {
        int c0 = q * 256 + w * 64;
        if (c0 < 1856) {
            int cc = c0 + l;
            int d = cc / 29, part = cc - d * 29;
            if (part > 27) part = 27;
            cp16_lds(lds + 32768 + (size_t)c0 * 16, Vg + (long)d * S_PAD + part * 8);
        }
    }
    // ---- Q fragments (direct global; rows i0 + w*16 + lr, clamped to valid range) ----
    int qr = i0 + w * 16 + lr;
    if (qr > S_PAD - 1) qr = S_PAD - 1;
    long qrow = (long)qr * 2304;
    f16x8 qf0 = *(const f16x8*)(Qb + qrow + quad * 8);
    f16x8 qf1 = *(const f16x8*)(Qb + qrow + 32 + quad * 8);
    __syncthreads();   // waits vmcnt(0): DMA complete

    // ---- QK^T: 14 j-tiles, K=64 (2 MFMA each) ----
    const f16_t* Ks = (const f16_t*)lds;
    floatx4 acc[14];
    #pragma unroll
    for (int jt = 0; jt < 14; jt++) {
        floatx4 a = (floatx4){0.f, 0.f, 0.f, 0.f};
        f16x8 k0 = *(const f16x8*)(Ks + (jt * 16 + lr) * 72 + quad * 8);
        f16x8 k1 = *(const f16x8*)(Ks + (jt * 16 + lr) * 72 + 32 + quad * 8);
        a = __builtin_amdgcn_mfma_f32_16x16x32_f16(qf0, k0, a, 0, 0, 0);
        a = __builtin_amdgcn_mfma_f32_16x16x32_f16(qf1, k1, a, 0, 0, 0);
        acc[jt] = a;
    }
    // ---- softmax over j (masked at S), stats per row via 16-lane butterflies ----
    float mx[4] = {-3.0e38f, -3.0e38f, -3.0e38f, -3.0e38f};
    #pragma unroll
    for (int jt = 0; jt < 14; jt++) {
        bool valid = (jt * 16 + lr) < S;
        #pragma unroll
        for (int rg = 0; rg < 4; rg++) {
            float v = valid ? acc[jt][rg] * 0.125f : -3.0e38f;
            acc[jt][rg] = v;
            mx[rg] = fmaxf(mx[rg], v);
        }
    }
    #pragma unroll
    for (int rg = 0; rg < 4; rg++)
        #pragma unroll
        for (int m = 1; m < 16; m <<= 1) mx[rg] = fmaxf(mx[rg], __shfl_xor(mx[rg], m));
    float sm[4] = {0.f, 0.f, 0.f, 0.f};
    #pragma unroll
    for (int jt = 0; jt < 14; jt++)
        #pragma unroll
        for (int rg = 0; rg < 4; rg++) {
            float e = __expf(acc[jt][rg] - mx[rg]);
            acc[jt][rg] = e; sm[rg] += e;
        }
    #pragma unroll
    for (int rg = 0; rg < 4; rg++)
        #pragma unroll
        for (int m = 1; m < 16; m <<= 1) sm[rg] += __shfl_xor(sm[rg], m);

    __syncthreads();   // all waves done reading Ksh -> safe to overwrite with P
    // ---- P: C-layout -> LDS (A-layout rows, stride 232), per-wave region ----
    f16_t* Pw = (f16_t*)lds + w * 16 * 232;
    #pragma unroll
    for (int jt = 0; jt < 14; jt++)
        #pragma unroll
        for (int rg = 0; rg < 4; rg++)
            Pw[(quad * 4 + rg) * 232 + jt * 16 + lr] = (f16_t)acc[jt][rg];

    // ---- PV: O[i][d] = sum_j P[i][j] * Vt[d][j], K=224 = 7 x 32 ----
    const f16_t* Vt = (const f16_t*)(lds + 32768);
    floatx4 oacc[4];
    #pragma unroll
    for (int dt = 0; dt < 4; dt++) oacc[dt] = (floatx4){0.f, 0.f, 0.f, 0.f};
    #pragma unroll
    for (int ks = 0; ks < 7; ks++) {
        f16x8 a = *(const f16x8*)(Pw + lr * 232 + ks * 32 + quad * 8);
        #pragma unroll
        for (int dt = 0; dt < 4; dt++) {
            f16x8 bb = *(const f16x8*)(Vt + (dt * 16 + lr) * 232 + ks * 32 + quad * 8);
            oacc[dt] = __builtin_amdgcn_mfma_f32_16x16x32_f16(a, bb, oacc[dt], 0, 0, 0);
        }
    }
    if (i0 + w * 16 < S_PAD) {     // wave-uniform row-validity guard
        float inv[4];
        #pragma unroll
        for (int rg = 0; rg < 4; rg++) inv[rg] = 1.0f / sm[rg];
        f16_t* dst = AO + (long)b * S_PAD * DM + h * HDIM;
        #pragma unroll
        for (int dt = 0; dt < 4; dt++)
            #pragma unroll
            for (int rg = 0; rg < 4; rg++)
                dst[(long)(i0 + w * 16 + quad * 4 + rg) * DM + dt * 16 + lr] = (f16_t)(oacc[dt][rg] * inv[rg]);
    }
}

// ---------------- routing ----------------
__global__ void cls_ln(const float* __restrict__ X, const float* __restrict__ gw,
                       const float* __restrict__ gb, float* __restrict__ q) {
    int b = blockIdx.x, t = threadIdx.x;
    const float* x = X + (long)b * S_PAD * DM;
    float v0 = x[t], v1 = x[t + 256], v2 = x[t + 512];
    float s = v0 + v1 + v2, ss = v0 * v0 + v1 * v1 + v2 * v2;
    #pragma unroll
    for (int off = 32; off; off >>= 1) { s += __shfl_down(s, off); ss += __shfl_down(ss, off); }
    __shared__ float sa[8];
    int w = t >> 6;
    if ((t & 63) == 0) { sa[w] = s; sa[4 + w] = ss; }
    __syncthreads();
    s = sa[0] + sa[1] + sa[2] + sa[3]; ss = sa[4] + sa[5] + sa[6] + sa[7];
    float mean = s * (1.0f / DM);
    float rs = rsqrtf(ss * (1.0f / DM) - mean * mean + LN_EPS);
    q[(long)b * DM + t]       = (v0 - mean) * rs * gw[t]       + gb[t];
    q[(long)b * DM + t + 256] = (v1 - mean) * rs * gw[t + 256] + gb[t + 256];
    q[(long)b * DM + t + 512] = (v2 - mean) * rs * gw[t + 512] + gb[t + 512];
}

__global__ void var_ssq(const float* __restrict__ var, float* __restrict__ ssq) {
    int p = blockIdx.x, chunk = blockIdx.y;   // grid (10, 36), 16384 elems per chunk
    const float* v = var + (long)p * DM * DM + (long)chunk * 16384;
    float s = 0.f;
    for (int i = threadIdx.x; i < 16384; i += 256) { float x = v[i]; s += x * x; }
    #pragma unroll
    for (int off = 32; off; off >>= 1) s += __shfl_down(s, off);
    __shared__ float sa[4];
    int w = threadIdx.x >> 6;
    if ((threadIdx.x & 63) == 0) sa[w] = s;
    __syncthreads();
    if (threadIdx.x == 0) atomicAdd(&ssq[p], sa[0] + sa[1] + sa[2] + sa[3]);
}

__global__ void route_coef(const float* __restrict__ ssq, const float* __restrict__ freq,
                           float* __restrict__ coef) {
    if (threadIdx.x == 0) {
        float fm = freq[0];
        for (int p = 1; p < NPOOL; p++) fm = fmaxf(fm, freq[p]);
        float w[NPOOL]; float n2 = 0.f;
        for (int p = 0; p < NPOOL; p++) { w[p] = fm - freq[p]; n2 += w[p] * w[p]; }
        float nrm = fmaxf(sqrtf(n2), 1e-12f);
        for (int p = 0; p < NPOOL; p++) {
            float wn = w[p] / nrm;
            coef[p] = 0.25f * logf(ssq[p]) + logf(fmaxf(wn, 1e-30f));
        }
    }
}

__global__ __launch_bounds__(256) void route_quad(const float* __restrict__ q,
        const float* __restrict__ kp, const float* __restrict__ iv,
        const float* __restrict__ coef, float* __restrict__ score) {
    int b = blockIdx.x, p = blockIdx.y, t = threadIdx.x;
    __shared__ float diff[DM];
    for (int e = t; e < DM; e += 256) diff[e] = q[(long)b * DM + e] - kp[(long)p * DM + e];
    __syncthreads();
    const float* M = iv + (long)p * DM * DM;
    float u0 = 0.f, u1 = 0.f, u2 = 0.f;
    for (int i = 0; i < DM; i++) {
        float di = diff[i];
        const float* r = M + (long)i * DM;
        u0 += di * r[t]; u1 += di * r[t + 256]; u2 += di * r[t + 512];
    }
    float part = u0 * diff[t] + u1 * diff[t + 256] + u2 * diff[t + 512];
    #pragma unroll
    for (int off = 32; off; off >>= 1) part += __shfl_down(part, off);
    __shared__ float sa[4];
    if ((t & 63) == 0) sa[t >> 6] = part;
    __syncthreads();
    if (t == 0) score[b * NPOOL + p] = -0.5f * (sa[0] + sa[1] + sa[2] + sa[3]) + coef[p];
}

__global__ void topk_kernel(const float* __restrict__ score, int* __restrict__ topk) {
    int b = threadIdx.x;
    if (b < NBATCH) {
        float s[NPOOL]; bool used[NPOOL];
        for (int p = 0; p < NPOOL; p++) { s[p] = score[b * NPOOL + p]; used[p] = false; }
        for (int k = 0; k < NSEL; k++) {
            int best = 0; float bv = 3.4e38f;
            for (int p = 0; p < NPOOL; p++)
                if (!used[p] && s[p] < bv) { bv = s[p]; best = p; }
            used[best] = true; topk[b * NSEL + k] = best;
        }
    }
}

// sx = [x0[:, :1] | prompts[topk]+pos0 | x0[:, 1:197]] ; rows>=222 zero
__global__ void assemble_sx(const float* __restrict__ X0, const float* __restrict__ prompts,
                            const float* __restrict__ pos, const int* __restrict__ topk,
                            float* __restrict__ X) {
    int s = blockIdx.x, b = blockIdx.y, t = threadIdx.x;
    long o = ((long)b * S_PAD + s) * DM;
    for (int e = t; e < DM; e += 256) {
        float v;
        if (s == 0) v = X0[(long)b * S_PAD * DM + e];
        else if (s <= 25) {
            int j = s - 1;
            int pr = topk[b * NSEL + j / NPLEN];
            v = prompts[((long)pr * NPLEN + j % NPLEN) * DM + e] + pos[e];
        } else if (s <= 221) {
            v = X0[((long)b * S_PAD + (s - 25)) * DM + e];
        } else v = 0.0f;
        X[o + e] = v;
    }
}

// feat[b] = mean_{j=1..25} LN(X[b,j]) * gw + gb
__global__ __launch_bounds__(256) void feat_ln_mean(const float* __restrict__ X,
        const float* __restrict__ gw, const float* __restrict__ gb, float* __restrict__ feat) {
    int b = blockIdx.x, t = threadIdx.x;
    __shared__ float sa[8];
    float f0 = 0.f, f1 = 0.f, f2 = 0.f;
    for (int j = 1; j <= NSEL * NPLEN; j++) {
        const float* x = X + ((long)b * S_PAD + j) * DM;
        float v0 = x[t], v1 = x[t + 256], v2 = x[t + 512];
        float s = v0 + v1 + v2, ss = v0 * v0 + v1 * v1 + v2 * v2;
        #pragma unroll
        for (int off = 32; off; off >>= 1) { s += __shfl_down(s, off); ss += __shfl_down(ss, off); }
        __syncthreads();
        int w = t >> 6;
        if ((t & 63) == 0) { sa[w] = s; sa[4 + w] = ss; }
        __syncthreads();
        s = sa[0] + sa[1] + sa[2] + sa[3]; ss = sa[4] + sa[5] + sa[6] + sa[7];
        float mean = s * (1.0f / DM);
        float rs = rsqrtf(ss * (1.0f / DM) - mean * mean + LN_EPS);
        f0 += (v0 - mean) * rs; f1 += (v1 - mean) * rs; f2 += (v2 - mean) * rs;
    }
    const float k = 1.0f / (NSEL * NPLEN);
    feat[(long)b * DM + t]       = f0 * k * gw[t]       + gb[t];
    feat[(long)b * DM + t + 256] = f1 * k * gw[t + 256] + gb[t + 256];
    feat[(long)b * DM + t + 512] = f2 * k * gw[t + 512] + gb[t + 512];
}

__global__ void head_gemm(const float* __restrict__ feat, const float* __restrict__ hw,
                          const float* __restrict__ hb, float* __restrict__ out) {
    int b = blockIdx.x, c = threadIdx.x;
    if (c < NCLS) {
        float a = hb[c];
        const float* f = feat + (long)b * DM;
        for (int k = 0; k < DM; k++) a += f[k] * hw[(long)k * NCLS + c];
        out[b * NCLS + c] = a;
    }
}

// ---------------- launch ----------------
extern "C" void kernel_launch(void* const* d_in, const int* in_sizes, int n_in,
                              void* d_out, int out_size, void* d_ws, size_t ws_size,
                              hipStream_t stream) {
    const float* inputs   = (const float*)d_in[0];
    const float* patch_w  = (const float*)d_in[1];
    const float* patch_b  = (const float*)d_in[2];
    const float* cls_tok  = (const float*)d_in[3];
    const float* pos_emb  = (const float*)d_in[4];
    const float* ln1_w    = (const float*)d_in[5];
    const float* ln1_b    = (const float*)d_in[6];
    const float* qkv_w    = (const float*)d_in[7];
    const float* qkv_b    = (const float*)d_in[8];
    const float* proj_w   = (const float*)d_in[9];
    const float* proj_b   = (const float*)d_in[10];
    const float* ln2_w    = (const float*)d_in[11];
    const float* ln2_b    = (const float*)d_in[12];
    const float* fc1_w    = (const float*)d_in[13];
    const float* fc1_b    = (const float*)d_in[14];
    const float* fc2_w    = (const float*)d_in[15];
    const float* fc2_b    = (const float*)d_in[16];
    const float* norm_w   = (const float*)d_in[17];
    const float* norm_b   = (const float*)d_in[18];
    const float* head_w   = (const float*)d_in[19];
    const float* head_b   = (const float*)d_in[20];
    const float* key_pool = (const float*)d_in[21];
    const float* freq     = (const float*)d_in[22];
    const float* prompts  = (const float*)d_in[23];
    const float* variance = (const float*)d_in[24];
    const float* inv_var  = (const float*)d_in[25];
    float* out = (float*)d_out;

    char* p = (char*)d_ws;
    auto alloc = [&](size_t bytes) { char* r = p; p += (bytes + 255) & ~(size_t)255; return r; };
    f16_t* WTpatch = (f16_t*)alloc(768UL * 768 * 2);
    f16_t* WTq  = (f16_t*)alloc(12UL * 2304 * 768 * 2);
    f16_t* WTpr = (f16_t*)alloc(12UL * 768 * 768 * 2);
    f16_t* WTf1 = (f16_t*)alloc(12UL * 3072 * 768 * 2);
    f16_t* WTf2 = (f16_t*)alloc(12UL * 768 * 3072 * 2);
    float*  X    = (float*)alloc((size_t)NTOK * DM * 4);
    float*  X0   = (float*)alloc((size_t)NTOK * DM * 4);
    f16_t* Hb   = (f16_t*)alloc((size_t)NTOK * DM * 2);
    f16_t* QKV  = (f16_t*)alloc((size_t)NTOK * 2304 * 2);
    f16_t* VTg  = (f16_t*)alloc(384UL * HDIM * S_PAD * 2);
    f16_t* AO   = (f16_t*)alloc((size_t)NTOK * DM * 2);
    char* RSC    = alloc(384UL * S_PAD * S_PAD * 4);  // MID f16 | PE f32 (disjoint lifetimes)
    char* RP     = alloc(384UL * S_PAD * S_PAD * 2);  // PATCH f16
    float* qv    = (float*)alloc(NBATCH * DM * 4);
    float* feat  = (float*)alloc(NBATCH * DM * 4);
    float* ssq   = (float*)alloc(NPOOL * 4);
    float* coef  = (float*)alloc(NPOOL * 4);
    float* score = (float*)alloc(NBATCH * NPOOL * 4);
    int*   tki   = (int*)alloc(NBATCH * NSEL * 4);
    f16_t* MID  = (f16_t*)RSC;
    float*  PE   = (float*)RSC;
    f16_t* PATCH= (f16_t*)RP;

    // ---- weights -> f16 transposed ----
    wconv_t<<<dim3(768/32, 768/32, 1), 256, 0, stream>>>(patch_w, WTpatch, 768, 768);
    wconv_t<<<dim3(2304/32, 768/32, 12), 256, 0, stream>>>(qkv_w, WTq, 768, 2304);
    wconv_t<<<dim3(768/32, 768/32, 12), 256, 0, stream>>>(proj_w, WTpr, 768, 768);
    wconv_t<<<dim3(3072/32, 768/32, 12), 256, 0, stream>>>(fc1_w, WTf1, 768, 3072);
    wconv_t<<<dim3(768/32, 3072/32, 12), 256, 0, stream>>>(fc2_w, WTf2, 3072, 768);

    // ---- embed ----
    patchify<<<dim3(S_PAD, NBATCH), 256, 0, stream>>>(inputs, PATCH);
    gemm_f16<0,64><<<dim3(112, 6), 256, 0, stream>>>(PATCH, WTpatch, patch_b, nullptr, PE, nullptr, 768, 768);
    assemble_x0<<<dim3(S_PAD, NBATCH), 256, 0, stream>>>(PE, cls_tok, pos_emb, X0, X);

    auto run_layers = [&](int S) {
        for (int l = 0; l < NLAYER; l++) {
            ln_to_f16<<<NTOK, 256, 0, stream>>>(X, ln1_w + l * DM, ln1_b + l * DM, Hb);
            gemm_f16<1,128><<<dim3(56, 18), 256, 0, stream>>>(Hb, WTq + (long)l * 2304 * 768,
                qkv_b + l * 2304, nullptr, nullptr, QKV, 2304, 768);
            v_trans<<<384, 256, 0, stream>>>(QKV, VTg);
            attn_fused<<<dim3(4, 384), 256, 0, stream>>>(QKV, VTg, AO, S);
            gemm_f16<2,64><<<dim3(112, 6), 256, 0, stream>>>(AO, WTpr + (long)l * 768 * 768,
                proj_b + l * DM, X, X, nullptr, 768, 768);
            ln_to_f16<<<NTOK, 256, 0, stream>>>(X, ln2_w + l * DM, ln2_b + l * DM, Hb);
            gemm_f16<3,128><<<dim3(56, 24), 256, 0, stream>>>(Hb, WTf1 + (long)l * 3072 * 768,
                fc1_b + l * DMLP, nullptr, nullptr, MID, 3072, 768);
            gemm_f16<2,64><<<dim3(112, 6), 256, 0, stream>>>(MID, WTf2 + (long)l * 768 * 3072,
                fc2_b + l * DM, X, X, nullptr, 768, 3072);
        }
    };

    // ---- pass 1 (S=197) ----
    run_layers(197);

    // ---- routing ----
    cls_ln<<<NBATCH, 256, 0, stream>>>(X, norm_w, norm_b, qv);
    hipMemsetAsync(ssq, 0, NPOOL * 4, stream);
    var_ssq<<<dim3(NPOOL, 36), 256, 0, stream>>>(variance, ssq);
    route_coef<<<1, 64, 0, stream>>>(ssq, freq, coef);
    route_quad<<<dim3(NBATCH, NPOOL), 256, 0, stream>>>(qv, key_pool, inv_var, coef, score);
    topk_kernel<<<1, 32, 0, stream>>>(score, tki);
    assemble_sx<<<dim3(S_PAD, NBATCH), 256, 0, stream>>>(X0, prompts, pos_emb, tki, X);

    // ---- pass 2 (S=222) ----
    run_layers(222);

    // ---- head ----
    feat_ln_mean<<<NBATCH, 256, 0, stream>>>(X, norm_w, norm_b, feat);
    head_gemm<<<NBATCH, 128, 0, stream>>>(feat, head_w, head_b, out);
    (void)in_sizes; (void)n_in; (void)out_size; (void)ws_size;
}